// Round 1
// baseline (280.426 us; speedup 1.0000x reference)
//
#include <hip/hip_runtime.h>
#include <hip/hip_bf16.h>
#include <hip/hip_fp16.h>

// FrameConsistencyLoss: mean over (N,64) of (proj_a - proj_b)^2 where
// proj_x[i] = x[i] @ W[ids_x[i]] + b[ids_x[i]], N=2e6, REL_DIM=14, CAN_DIM=64, 4 experts.
//
// Strategy: expert-embedded GEMM. Row i is embedded into K=64:
//   emb[14*e + k] = x[k] for e == id, emb[56+e] = 1.0 (one-hot -> bias via W~ rows 56..59),
//   everything else 0. W~ (64x64) stacks [W_0;W_1;W_2;W_3;bias;0pad] so
//   emb_a @ W~ = a@W[ea] + b[ea] exactly. diff = emb_a@W~ - emb_b@W~ computed in one
//   MFMA accumulator chain using +W~ and -W~ register-resident B-fragments.
// Loss = sum of squares of ALL output elements -> invariant to any row/col/k
// permutation of the MFMA fragment layouts (A and B share the same k-structure).

#define N_ROWS   2000000
#define CHUNK    64                    // rows per wave-iteration (lane = row)
#define N_CHUNKS (N_ROWS / CHUNK)      // 31250, exact
#define LDSP     72                    // ushort pitch per LDS row (64 + 8 pad -> bank rotate)

typedef _Float16       h8  __attribute__((ext_vector_type(8)));
typedef float          f4  __attribute__((ext_vector_type(4)));
typedef unsigned short us8 __attribute__((ext_vector_type(8)));

__device__ __forceinline__ unsigned short f2h_bits(float x) {
    return __builtin_bit_cast(unsigned short, (_Float16)x);
}

__global__ void __launch_bounds__(64)
frame_loss_mfma(const float* __restrict__ A, const float* __restrict__ B,
                const int* __restrict__ IDA, const int* __restrict__ IDB,
                const float* __restrict__ W, const float* __restrict__ BIAS,
                float* __restrict__ out)
{
    __shared__ unsigned short sA[CHUNK * LDSP];   // embedded a rows, f16 bits
    __shared__ unsigned short sB[CHUNK * LDSP];   // embedded b rows, f16 bits

    const int lane = threadIdx.x & 63;
    const int sub  = lane & 15;   // n (col) / m (row) index within 16
    const int quad = lane >> 4;   // k-group

    // ---- Build W~ B-operand fragments in registers (+ negated copies), once ----
    // Assumed B layout for mfma_f32_16x16x32: col = lane&15, k = (lane>>4)*8 + j.
    // (Consistent with the A-side staging below; k-permutation errors cancel.)
    h8 wf[8], nwf[8];
#pragma unroll
    for (int ct = 0; ct < 4; ++ct) {
#pragma unroll
        for (int s = 0; s < 2; ++s) {
            const int c = ct * 16 + sub;
            us8 bits;
#pragma unroll
            for (int j = 0; j < 8; ++j) {
                const int k = s * 32 + quad * 8 + j;
                float v = 0.0f;
                if (k < 56) {
                    const int e = k / 14;          // compile-time after unroll? k is runtime (quad) — fine, cheap once
                    const int kk = k - e * 14;
                    v = W[(e * 14 + kk) * 64 + c];
                } else if (k < 60) {
                    v = BIAS[(k - 56) * 64 + c];
                }
                bits[j] = f2h_bits(v);
            }
            wf[ct * 2 + s] = __builtin_bit_cast(h8, bits);
            us8 nb = bits ^ (unsigned short)0x8000;   // flip sign bit of every f16
            nwf[ct * 2 + s] = __builtin_bit_cast(h8, nb);
        }
    }

    float lsum = 0.0f;
    unsigned int* const rowA32 = (unsigned int*)(sA + lane * LDSP);
    unsigned int* const rowB32 = (unsigned int*)(sB + lane * LDSP);

    for (int chunk = blockIdx.x; chunk < N_CHUNKS; chunk += gridDim.x) {
        const int row = chunk * CHUNK + lane;
        const float2* ap = (const float2*)(A + (size_t)row * 14);  // 56B rows, 8B aligned
        const float2* bp = (const float2*)(B + (size_t)row * 14);
        float2 av[7], bv[7];
#pragma unroll
        for (int t = 0; t < 7; ++t) av[t] = ap[t];
#pragma unroll
        for (int t = 0; t < 7; ++t) bv[t] = bp[t];
        const int ea = IDA[row];
        const int eb = IDB[row];

        // zero my embedded rows (144 B each = 9 x b128)
        const us8 z = {0, 0, 0, 0, 0, 0, 0, 0};
#pragma unroll
        for (int t = 0; t < 9; ++t) ((us8*)rowA32)[t] = z;
#pragma unroll
        for (int t = 0; t < 9; ++t) ((us8*)rowB32)[t] = z;

        // scatter: 7 packed f16 pairs at ushort offset 14*e (uint word 7*e), one-hot at 56+e
#pragma unroll
        for (int t = 0; t < 7; ++t)
            rowA32[7 * ea + t] = (unsigned)f2h_bits(av[t].x) | ((unsigned)f2h_bits(av[t].y) << 16);
        rowA32[28 + (ea >> 1)] = 0x3C00u << (16 * (ea & 1));
#pragma unroll
        for (int t = 0; t < 7; ++t)
            rowB32[7 * eb + t] = (unsigned)f2h_bits(bv[t].x) | ((unsigned)f2h_bits(bv[t].y) << 16);
        rowB32[28 + (eb >> 1)] = 0x3C00u << (16 * (eb & 1));

        __syncthreads();

        // 4 M-tiles of 16 rows; per tile: 4 col-tiles x (2 k-steps x {a,+W / b,-W})
#pragma unroll
        for (int t = 0; t < 4; ++t) {
            const unsigned short* fa = sA + (t * 16 + sub) * LDSP + quad * 8;
            const unsigned short* fb = sB + (t * 16 + sub) * LDSP + quad * 8;
            h8 a0 = __builtin_bit_cast(h8, *(const us8*)fa);
            h8 a1 = __builtin_bit_cast(h8, *(const us8*)(fa + 32));
            h8 b0 = __builtin_bit_cast(h8, *(const us8*)fb);
            h8 b1 = __builtin_bit_cast(h8, *(const us8*)(fb + 32));
#pragma unroll
            for (int ct = 0; ct < 4; ++ct) {
                f4 acc = {0.0f, 0.0f, 0.0f, 0.0f};
                acc = __builtin_amdgcn_mfma_f32_16x16x32_f16(a0, wf[ct * 2 + 0], acc, 0, 0, 0);
                acc = __builtin_amdgcn_mfma_f32_16x16x32_f16(a1, wf[ct * 2 + 1], acc, 0, 0, 0);
                acc = __builtin_amdgcn_mfma_f32_16x16x32_f16(b0, nwf[ct * 2 + 0], acc, 0, 0, 0);
                acc = __builtin_amdgcn_mfma_f32_16x16x32_f16(b1, nwf[ct * 2 + 1], acc, 0, 0, 0);
                lsum += acc[0] * acc[0] + acc[1] * acc[1] + acc[2] * acc[2] + acc[3] * acc[3];
            }
        }
        __syncthreads();
    }

    // wave reduction then one atomic per wave (scaled -> mean)
#pragma unroll
    for (int off = 32; off > 0; off >>= 1)
        lsum += __shfl_down(lsum, off, 64);
    if (lane == 0)
        atomicAdd(out, lsum * (1.0f / 128000000.0f));   // 1 / (N * 64)
}

extern "C" void kernel_launch(void* const* d_in, const int* in_sizes, int n_in,
                              void* d_out, int out_size, void* d_ws, size_t ws_size,
                              hipStream_t stream) {
    const float* A    = (const float*)d_in[0];
    const float* B    = (const float*)d_in[1];
    const int*   IDA  = (const int*)d_in[2];
    const int*   IDB  = (const int*)d_in[3];
    const float* W    = (const float*)d_in[4];
    const float* BIAS = (const float*)d_in[5];
    float* out = (float*)d_out;

    hipMemsetAsync(out, 0, sizeof(float), stream);   // harness poisons d_out with 0xAA
    frame_loss_mfma<<<dim3(4096), dim3(64), 0, stream>>>(A, B, IDA, IDB, W, BIAS, out);
}